// Round 3
// baseline (346.054 us; speedup 1.0000x reference)
//
#include <hip/hip_runtime.h>
#include <cstdint>
#include <cstddef>

// Problem constants: B=8, S=2048, H=512, M=4096 -> R = B*S = 16384 rows.
#define R_TOTAL 16384
#define H_DIM   512
#define M_DIM   4096

typedef unsigned short u16;
typedef short bf16x8 __attribute__((ext_vector_type(8)));   // 8 bf16 in 4 VGPRs
typedef float f32x4  __attribute__((ext_vector_type(4)));

typedef const __attribute__((address_space(1))) void* gp_t;
typedef __attribute__((address_space(3))) void* lp_t;

// fp32 -> bf16 round-to-nearest-even
__device__ __forceinline__ u16 f2b(float f) {
  union { float f; uint32_t u; } v; v.f = f;
  uint32_t u = v.u + (0x7FFFu + ((v.u >> 16) & 1u));
  return (u16)(u >> 16);
}

// ---------------- elementwise fp32 -> bf16 (n4 = n/4 float4 groups) ----------
__global__ void k_f2bf(const float* __restrict__ in, u16* __restrict__ out, int n4) {
  int i = blockIdx.x * blockDim.x + threadIdx.x;
  if (i < n4) {
    float4 v = ((const float4*)in)[i];
    ushort4 o;
    o.x = f2b(v.x); o.y = f2b(v.y); o.z = f2b(v.z); o.w = f2b(v.w);
    ((ushort4*)out)[i] = o;
  }
}

// ------------- row L2-normalize: fp32 [rows,512] -> bf16 [rows,512] ----------
// one wave per row, 4 waves per block
__global__ void k_rownorm(const float* __restrict__ in, u16* __restrict__ out) {
  int row  = blockIdx.x * 4 + (threadIdx.x >> 6);
  int lane = threadIdx.x & 63;
  const float4* rp = (const float4*)(in + (size_t)row * H_DIM);
  float4 a = rp[lane];
  float4 b = rp[lane + 64];
  float ss = a.x*a.x + a.y*a.y + a.z*a.z + a.w*a.w
           + b.x*b.x + b.y*b.y + b.z*b.z + b.w*b.w;
  #pragma unroll
  for (int d = 1; d < 64; d <<= 1) ss += __shfl_xor(ss, d, 64);
  float s = rsqrtf(ss + 1e-6f);
  ushort4 oa, ob;
  oa.x = f2b(a.x*s); oa.y = f2b(a.y*s); oa.z = f2b(a.z*s); oa.w = f2b(a.w*s);
  ob.x = f2b(b.x*s); ob.y = f2b(b.y*s); ob.z = f2b(b.z*s); ob.w = f2b(b.w*s);
  ushort4* op = (ushort4*)(out + (size_t)row * H_DIM);
  op[lane]      = oa;
  op[lane + 64] = ob;
}

// ---- compaction: scan usage[4096] -> idx map + meta -------------------------
// meta[0]=count, meta[1]=K_eff=round128(count), meta[2]=K_eff/32, meta[3]=K_eff/128
__global__ void k_compact(const int* __restrict__ usage, int* __restrict__ idx,
                          int* __restrict__ meta) {
  __shared__ int cnt[256];
  int t = threadIdx.x;
  int base = t * 16;
  int c = 0;
  #pragma unroll
  for (int i = 0; i < 16; ++i) c += (usage[base + i] > 0) ? 1 : 0;
  cnt[t] = c;
  __syncthreads();
  for (int d = 1; d < 256; d <<= 1) {           // inclusive Hillis-Steele scan
    int v = (t >= d) ? cnt[t - d] : 0;
    __syncthreads();
    cnt[t] += v;
    __syncthreads();
  }
  int pos = cnt[t] - c;                          // exclusive prefix
  for (int i = 0; i < 16; ++i)
    if (usage[base + i] > 0) idx[pos++] = base + i;
  if (t == 0) {
    int total = cnt[255];
    int keff = ((total + 127) >> 7) << 7;
    meta[0] = total; meta[1] = keff; meta[2] = keff >> 5; meta[3] = keff >> 7;
  }
}

// ---- gather + L2-normalize keys into compacted bank (zeros padding) ---------
__global__ void k_gather_norm(const float* __restrict__ in, const int* __restrict__ idx,
                              const int* __restrict__ meta, u16* __restrict__ out) {
  int j    = blockIdx.x * 4 + (threadIdx.x >> 6);
  int lane = threadIdx.x & 63;
  int count = meta[0];
  ushort4* op = (ushort4*)(out + (size_t)j * H_DIM);
  if (j >= count) {                 // wave-uniform
    ushort4 z = {0, 0, 0, 0};
    op[lane] = z; op[lane + 64] = z;
    return;
  }
  int src = idx[j];
  const float4* rp = (const float4*)(in + (size_t)src * H_DIM);
  float4 a = rp[lane];
  float4 b = rp[lane + 64];
  float ss = a.x*a.x + a.y*a.y + a.z*a.z + a.w*a.w
           + b.x*b.x + b.y*b.y + b.z*b.z + b.w*b.w;
  #pragma unroll
  for (int d = 1; d < 64; d <<= 1) ss += __shfl_xor(ss, d, 64);
  float s = rsqrtf(ss + 1e-6f);
  ushort4 oa, ob;
  oa.x = f2b(a.x*s); oa.y = f2b(a.y*s); oa.z = f2b(a.z*s); oa.w = f2b(a.w*s);
  ob.x = f2b(b.x*s); ob.y = f2b(b.y*s); ob.z = f2b(b.z*s); ob.w = f2b(b.w*s);
  op[lane]      = oa;
  op[lane + 64] = ob;
}

// ---- gather + transpose + convert: V fp32 rows -> Vt bf16 [512, 4096] -------
__global__ void k_gather_t(const float* __restrict__ in, const int* __restrict__ idx,
                           const int* __restrict__ meta, u16* __restrict__ out) {
  __shared__ u16 tile[32][33];
  int tx = threadIdx.x & 31, ty = threadIdx.x >> 5;   // 32x8
  int m0 = blockIdx.y * 32, v0 = blockIdx.x * 32;
  int count = meta[0];
  #pragma unroll
  for (int j = 0; j < 4; ++j) {
    int m = m0 + ty + j * 8;
    u16 val = 0;
    if (m < count) {
      int src = idx[m];
      val = f2b(in[(size_t)src * H_DIM + v0 + tx]);
    }
    tile[ty + j*8][tx] = val;
  }
  __syncthreads();
  #pragma unroll
  for (int j = 0; j < 4; ++j)
    out[(size_t)(v0 + ty + j*8) * M_DIM + m0 + tx] = tile[tx][ty + j*8];
}

// ---- reduce partial row sums -> reciprocal (dynamic npart from meta) --------
__global__ void k_reduce_l(const float* __restrict__ lpart, float* __restrict__ linv,
                           const int* __restrict__ meta) {
  int r = blockIdx.x * blockDim.x + threadIdx.x;
  int n = meta[3];
  float s = 0.0f;
  for (int i = 0; i < n; ++i) s += lpart[(size_t)r * 32 + i];
  linv[r] = 1.0f / s;
}

// =============================================================================
// BT-layout GEMM: C[r,n] = sum_k A[r,k] * B[n,k]   (A: [Rr,K] bf16, B: [N,K] bf16)
// 128x128 tile, BK=32, 256 threads = 4 waves, each wave 64x64 via 4x4 of 16x16x32.
//
// LDS layout (bank-conflict-minimal): each 16-row x 32-col slab is stored as
// [chunk(4)][row(16)][8 elems]; element (R,k) at slab (R>>4), index
// (k>>3)*128 + (R&15)*8 + (k&7). Staged via global_load_lds with lane ->
// (row=lane&15, chunk=lane>>4) so the DMA's base+lane*16 lands exactly there.
// Fragment reads then sweep 256 B contiguous per quarter-wave -> no excess
// bank conflicts (was ~8-way with row-major slabs).
//
// EPI 0: outf[r*N+n] = C + bias[n]  (fp32); one col-block per blockIdx.x
// EPI 1: col-block loop cb = bx, bx+16, ... while cb*128 < meta[1] (no dead
//        blocks in the grid!); P = (n<meta[0]) ? exp(10*C) : 0 -> outh bf16;
//        per-row partial sums -> lpart[row*32 + cb]
// EPI 2: outh bf16 = C * linv[r]; kiters = meta[2]
// =============================================================================
template<int EPI>
__global__ __launch_bounds__(256)
void k_gemm_bt(const u16* __restrict__ A, const u16* __restrict__ B,
               int N, int K,
               const int* __restrict__ meta,
               float* __restrict__ outf, u16* __restrict__ outh,
               const float* __restrict__ bias,
               float* __restrict__ lpart,
               const float* __restrict__ linv) {
  __shared__ u16 Ah[128 * 32];
  __shared__ u16 Bh[128 * 32];
  __shared__ float lsh[128];

  const int tid  = threadIdx.x;
  const int wave = tid >> 6, lane = tid & 63;
  const int row0 = blockIdx.y * 128;
  const int wr = (wave >> 1) * 64, wc = (wave & 1) * 64;

  int kiters, cb_end, cb_step;
  if (EPI == 1)      { kiters = K >> 5;   cb_end = meta[1] >> 7;    cb_step = 16; }
  else if (EPI == 2) { kiters = meta[2];  cb_end = blockIdx.x + 1;  cb_step = 1; }
  else               { kiters = K >> 5;   cb_end = blockIdx.x + 1;  cb_step = 1; }

  // staging lane map: row = lane&15 within a 16-row slab, k-chunk = lane>>4
  const int srow   = lane & 15;
  const int schunk = lane >> 4;
  const size_t aOff0 = (size_t)(row0 + wave * 16 + srow)       * (size_t)K + schunk * 8;
  const size_t aOff1 = (size_t)(row0 + (wave + 4) * 16 + srow) * (size_t)K + schunk * 8;
  u16* ldsA0 = &Ah[(wave)     * 512];
  u16* ldsA1 = &Ah[(wave + 4) * 512];
  u16* ldsB0 = &Bh[(wave)     * 512];
  u16* ldsB1 = &Bh[(wave + 4) * 512];

  const int fr = lane & 15;         // fragment row (A: m, B: n)
  const int q4 = lane >> 4;         // fragment k-chunk (k = q4*8 + e)

  for (int cb = blockIdx.x; cb < cb_end; cb += cb_step) {
    const int col0 = cb << 7;
    __syncthreads();                            // guard lsh reuse across cb iters
    if (EPI == 1 && tid < 128) lsh[tid] = 0.0f;

    const size_t bOff0 = (size_t)(col0 + wave * 16 + srow)       * (size_t)K + schunk * 8;
    const size_t bOff1 = (size_t)(col0 + (wave + 4) * 16 + srow) * (size_t)K + schunk * 8;

    f32x4 acc[4][4];
    const f32x4 z = {0.0f, 0.0f, 0.0f, 0.0f};
    #pragma unroll
    for (int i = 0; i < 4; ++i)
      #pragma unroll
      for (int j = 0; j < 4; ++j) acc[i][j] = z;

    for (int it = 0; it < kiters; ++it) {
      const int k0 = it << 5;
      __syncthreads();   // prior iteration's LDS reads drained
      __builtin_amdgcn_global_load_lds((gp_t)(A + aOff0 + k0), (lp_t)ldsA0, 16, 0, 0);
      __builtin_amdgcn_global_load_lds((gp_t)(A + aOff1 + k0), (lp_t)ldsA1, 16, 0, 0);
      __builtin_amdgcn_global_load_lds((gp_t)(B + bOff0 + k0), (lp_t)ldsB0, 16, 0, 0);
      __builtin_amdgcn_global_load_lds((gp_t)(B + bOff1 + k0), (lp_t)ldsB1, 16, 0, 0);
      __syncthreads();   // staging drained (vmcnt(0) before barrier)

      bf16x8 af[4], bfv[4];
      #pragma unroll
      for (int i = 0; i < 4; ++i)
        af[i] = *(const bf16x8*)&Ah[((wr >> 4) + i) * 512 + q4 * 128 + fr * 8];
      #pragma unroll
      for (int j = 0; j < 4; ++j)
        bfv[j] = *(const bf16x8*)&Bh[((wc >> 4) + j) * 512 + q4 * 128 + fr * 8];

      #pragma unroll
      for (int i = 0; i < 4; ++i)
        #pragma unroll
        for (int j = 0; j < 4; ++j)
          acc[i][j] = __builtin_amdgcn_mfma_f32_16x16x32_bf16(af[i], bfv[j], acc[i][j], 0, 0, 0);
    }

    // Epilogue. C/D layout per 16x16 tile: col = lane&15, row = (lane>>4)*4 + reg.
    if (EPI == 0) {
      #pragma unroll
      for (int i = 0; i < 4; ++i) {
        int growb = row0 + wr + i * 16 + (lane >> 4) * 4;
        #pragma unroll
        for (int j = 0; j < 4; ++j) {
          int gcol = col0 + wc + j * 16 + fr;
          float bv = bias[gcol];
          #pragma unroll
          for (int r = 0; r < 4; ++r)
            outf[(size_t)(growb + r) * (size_t)N + gcol] = acc[i][j][r] + bv;
        }
      }
    } else if (EPI == 1) {
      const int count = meta[0];
      #pragma unroll
      for (int i = 0; i < 4; ++i) {
        #pragma unroll
        for (int r = 0; r < 4; ++r) {
          int lrow = wr + i * 16 + (lane >> 4) * 4 + r;
          size_t grow = (size_t)(row0 + lrow);
          float s = 0.0f;
          #pragma unroll
          for (int j = 0; j < 4; ++j) {
            int gcol = col0 + wc + j * 16 + fr;
            float p = (gcol < count) ? __expf(acc[i][j][r] * 10.0f) : 0.0f;
            outh[grow * (size_t)N + gcol] = f2b(p);
            s += p;
          }
          #pragma unroll
          for (int d = 1; d < 16; d <<= 1) s += __shfl_xor(s, d, 64);
          if (fr == 0) atomicAdd(&lsh[lrow], s);
        }
      }
      __syncthreads();
      if (tid < 128)
        lpart[(size_t)(row0 + tid) * 32 + cb] = lsh[tid];
    } else {  // EPI == 2
      #pragma unroll
      for (int i = 0; i < 4; ++i) {
        #pragma unroll
        for (int r = 0; r < 4; ++r) {
          int grow = row0 + wr + i * 16 + (lane >> 4) * 4 + r;
          float sc = linv[grow];
          #pragma unroll
          for (int j = 0; j < 4; ++j) {
            int gcol = col0 + wc + j * 16 + fr;
            outh[(size_t)grow * (size_t)N + gcol] = f2b(acc[i][j][r] * sc);
          }
        }
      }
    }
  }
}

extern "C" void kernel_launch(void* const* d_in, const int* in_sizes, int n_in,
                              void* d_out, int out_size, void* d_ws, size_t ws_size,
                              hipStream_t stream) {
  const float* hidden = (const float*)d_in[0];   // [16384, 512]
  const float* mkeys  = (const float*)d_in[1];   // [4096, 512]
  const float* mvals  = (const float*)d_in[2];   // [4096, 512]
  const float* Wk     = (const float*)d_in[3];   // [512, 512]
  const float* bk     = (const float*)d_in[4];   // [512]
  const float* Wo     = (const float*)d_in[5];   // [512, 512]
  const float* bo     = (const float*)d_in[6];   // [512]
  const int*   usage  = (const int*)d_in[7];     // [4096]
  (void)in_sizes; (void)n_in; (void)out_size; (void)ws_size;

  char* ws = (char*)d_ws;
  // hb region [0, 16 MB): bf16 hidden during q-chain; AFTER q-chain it is dead
  // and its first 16 KB + 16 B are reused for idx/meta (footprint unchanged).
  u16*   hb    = (u16*)(ws + 0);           //  16,777,216  hidden bf16 (early)
  int*   idx   = (int*)(ws + 0);           //      16,384  compacted->orig map (late)
  int*   meta  = (int*)(ws + 16384);       //          16  {count, K_eff, K_eff/32, K_eff/128}
  u16*   wkb   = (u16*)(ws + 16777216);    //     524,288  Wk bf16
  u16*   wob   = (u16*)(ws + 17301504);    //     524,288  Wo bf16
  u16*   mkn   = (u16*)(ws + 17825792);    //   4,194,304  compacted normalized keys bf16
  u16*   vt    = (u16*)(ws + 22020096);    //   4,194,304  compacted V^T bf16 [512,4096]
  u16*   qn    = (u16*)(ws + 26214400);    //  16,777,216  normalized q bf16
  float* q     = (float*)(ws + 42991616);  //  33,554,432  q fp32 (aliases P; dead before P written)
  u16*   P     = (u16*)(ws + 42991616);    // 134,217,728  exp-scores bf16 [16384,4096]
  float* lpart = (float*)(ws + 177209344); //   2,097,152  row-sum partials [16384,32]
  float* linv  = (float*)(ws + 179306496); //      65,536  1/rowsum [16384]
  u16*   retr  = (u16*)(ws + 179372032);   //  16,777,216  retrieved bf16
  // total: 196,149,248 bytes

  // --- q-projection chain first (so hb can be reused for idx/meta) ---
  k_f2bf<<<8192, 256, 0, stream>>>(hidden, hb, 2097152);
  k_f2bf<<<256, 256, 0, stream>>>(Wk, wkb, 65536);
  k_f2bf<<<256, 256, 0, stream>>>(Wo, wob, 65536);

  // q = hidden @ Wk^T + bk  (fp32 out)
  k_gemm_bt<0><<<dim3(4, 128), 256, 0, stream>>>(hb, wkb, 512, 512,
      nullptr, q, nullptr, bk, nullptr, nullptr);
  // qn = rownorm(q) bf16
  k_rownorm<<<4096, 256, 0, stream>>>(q, qn);                            // 16384 rows

  // --- compaction of the memory bank (hb now dead) ---
  k_compact<<<1, 256, 0, stream>>>(usage, idx, meta);
  k_gather_norm<<<1024, 256, 0, stream>>>(mkeys, idx, meta, mkn);        // 4096 slots
  k_gather_t<<<dim3(16, 128), 256, 0, stream>>>(mvals, idx, meta, vt);

  // P = exp(10 * qn @ mkn^T) over active slots, partial row sums.
  // Grid has NO dead blocks: 16 col-block slots, each loops cb += 16 while
  // cb*128 < K_eff (usually one trip; two when count > 2048).
  k_gemm_bt<1><<<dim3(16, 128), 256, 0, stream>>>(qn, mkn, 4096, 512,
      meta, nullptr, P, nullptr, lpart, nullptr);
  k_reduce_l<<<64, 256, 0, stream>>>(lpart, linv, meta);

  // retrieved = (P @ Vt^T) * linv[row]  bf16   (K-loop trips = meta[2])
  k_gemm_bt<2><<<dim3(4, 128), 256, 0, stream>>>(P, vt, 512, 4096,
      meta, nullptr, retr, nullptr, nullptr, linv);

  // out = retrieved @ Wo^T + bo  (fp32)
  k_gemm_bt<0><<<dim3(4, 128), 256, 0, stream>>>(retr, wob, 512, 512,
      nullptr, (float*)d_out, nullptr, bo, nullptr, nullptr);
}

// Round 4
// 315.439 us; speedup vs baseline: 1.0971x; 1.0971x over previous
//
#include <hip/hip_runtime.h>
#include <cstdint>
#include <cstddef>

// Problem constants: B=8, S=2048, H=512, M=4096 -> R = B*S = 16384 rows.
#define H_DIM   512
#define M_DIM   4096

typedef unsigned short u16;
typedef short bf16x8 __attribute__((ext_vector_type(8)));   // 8 bf16 in 4 VGPRs
typedef float f32x4  __attribute__((ext_vector_type(4)));

typedef const __attribute__((address_space(1))) void* gp_t;
typedef __attribute__((address_space(3))) void* lp_t;

// fp32 -> bf16 round-to-nearest-even
__device__ __forceinline__ u16 f2b(float f) {
  union { float f; uint32_t u; } v; v.f = f;
  uint32_t u = v.u + (0x7FFFu + ((v.u >> 16) & 1u));
  return (u16)(u >> 16);
}

// ---------------- elementwise fp32 -> bf16 (n4 = n/4 float4 groups) ----------
__global__ void k_f2bf(const float* __restrict__ in, u16* __restrict__ out, int n4) {
  int i = blockIdx.x * blockDim.x + threadIdx.x;
  if (i < n4) {
    float4 v = ((const float4*)in)[i];
    ushort4 o;
    o.x = f2b(v.x); o.y = f2b(v.y); o.z = f2b(v.z); o.w = f2b(v.w);
    ((ushort4*)out)[i] = o;
  }
}

// ---- compaction: scan usage[4096] -> idx map + meta -------------------------
// meta[0]=count, meta[1]=K_eff=round128(count), meta[2]=K_eff/32, meta[3]=K_eff/128
__global__ void k_compact(const int* __restrict__ usage, int* __restrict__ idx,
                          int* __restrict__ meta) {
  __shared__ int cnt[256];
  int t = threadIdx.x;
  int base = t * 16;
  int c = 0;
  #pragma unroll
  for (int i = 0; i < 16; ++i) c += (usage[base + i] > 0) ? 1 : 0;
  cnt[t] = c;
  __syncthreads();
  for (int d = 1; d < 256; d <<= 1) {           // inclusive Hillis-Steele scan
    int v = (t >= d) ? cnt[t - d] : 0;
    __syncthreads();
    cnt[t] += v;
    __syncthreads();
  }
  int pos = cnt[t] - c;                          // exclusive prefix
  for (int i = 0; i < 16; ++i)
    if (usage[base + i] > 0) idx[pos++] = base + i;
  if (t == 0) {
    int total = cnt[255];
    int keff = ((total + 127) >> 7) << 7;
    meta[0] = total; meta[1] = keff; meta[2] = keff >> 5; meta[3] = keff >> 7;
  }
}

// ---- gather + L2-normalize keys into compacted bank (zeros padding) ---------
__global__ void k_gather_norm(const float* __restrict__ in, const int* __restrict__ idx,
                              const int* __restrict__ meta, u16* __restrict__ out) {
  int j    = blockIdx.x * 4 + (threadIdx.x >> 6);
  int lane = threadIdx.x & 63;
  int count = meta[0];
  ushort4* op = (ushort4*)(out + (size_t)j * H_DIM);
  if (j >= count) {                 // wave-uniform
    ushort4 z = {0, 0, 0, 0};
    op[lane] = z; op[lane + 64] = z;
    return;
  }
  int src = idx[j];
  const float4* rp = (const float4*)(in + (size_t)src * H_DIM);
  float4 a = rp[lane];
  float4 b = rp[lane + 64];
  float ss = a.x*a.x + a.y*a.y + a.z*a.z + a.w*a.w
           + b.x*b.x + b.y*b.y + b.z*b.z + b.w*b.w;
  #pragma unroll
  for (int d = 1; d < 64; d <<= 1) ss += __shfl_xor(ss, d, 64);
  float s = rsqrtf(ss + 1e-6f);
  ushort4 oa, ob;
  oa.x = f2b(a.x*s); oa.y = f2b(a.y*s); oa.z = f2b(a.z*s); oa.w = f2b(a.w*s);
  ob.x = f2b(b.x*s); ob.y = f2b(b.y*s); ob.z = f2b(b.z*s); ob.w = f2b(b.w*s);
  op[lane]      = oa;
  op[lane + 64] = ob;
}

// ---- gather + convert: mvals fp32 rows -> compacted bf16 rows (zero pad) ----
__global__ void k_gather(const float* __restrict__ in, const int* __restrict__ idx,
                         const int* __restrict__ meta, u16* __restrict__ out) {
  int j    = blockIdx.x * 4 + (threadIdx.x >> 6);
  int lane = threadIdx.x & 63;
  int count = meta[0];
  ushort4* op = (ushort4*)(out + (size_t)j * H_DIM);
  if (j >= count) {                 // wave-uniform
    ushort4 z = {0, 0, 0, 0};
    op[lane] = z; op[lane + 64] = z;
    return;
  }
  int src = idx[j];
  const float4* rp = (const float4*)(in + (size_t)src * H_DIM);
  float4 a = rp[lane];
  float4 b = rp[lane + 64];
  ushort4 oa, ob;
  oa.x = f2b(a.x); oa.y = f2b(a.y); oa.z = f2b(a.z); oa.w = f2b(a.w);
  ob.x = f2b(b.x); ob.y = f2b(b.y); ob.z = f2b(b.z); ob.w = f2b(b.w);
  op[lane]      = oa;
  op[lane + 64] = ob;
}

// ---- rsqQ[r] = rsqrt(sum of 4 qss partials + eps) ---------------------------
__global__ void k_rsq(const float* __restrict__ qss, float* __restrict__ rsq) {
  int r = blockIdx.x * blockDim.x + threadIdx.x;
  float s = qss[r*4] + qss[r*4+1] + qss[r*4+2] + qss[r*4+3];
  rsq[r] = rsqrtf(s + 1e-6f);
}

// ---- reduce partial row sums -> reciprocal (dynamic npart from meta) --------
__global__ void k_reduce_l(const float* __restrict__ lpart, float* __restrict__ linv,
                           const int* __restrict__ meta) {
  int r = blockIdx.x * blockDim.x + threadIdx.x;
  int n = meta[3];
  float s = 0.0f;
  for (int i = 0; i < n; ++i) s += lpart[(size_t)r * 32 + i];
  linv[r] = 1.0f / s;
}

// =============================================================================
// BT-layout GEMM: C[r,n] = sum_k A[r,k] * B[n,k]
// 128x128 tile, BK=32, 256 threads = 4 waves, each wave 64x64 via 4x4 of 16x16x32.
// Conflict-free LDS: 16-row slab stored [chunk(4)][row(16)][8]; staged by
// global_load_lds with lane -> (row=lane&15, chunk=lane>>4).
//
// EPI_QPROJ: out qb bf16 = C + bias; per-row partial sum of squares -> aux[row*4+cb]
// EPI_MW   : out MWt bf16 = C  (cb-loop over meta[1]/128, step 16)
// EPI_P    : XCD-swizzled rb; P = (n<meta[0]) ? exp(10*C*rowscale[r]) : 0 -> bf16;
//            per-row partial sums -> aux[row*32+cb]  (cb-loop, step 16)
// EPI_OUT  : XCD-swizzled rb; kiters=meta[2]; outf = C*rowscale[r] + bias[n] (fp32)
// =============================================================================
#define EPI_QPROJ 0
#define EPI_MW    1
#define EPI_P     2
#define EPI_OUT   3

template<int EPI>
__global__ __launch_bounds__(256)
void k_gemm_bt(const u16* __restrict__ A, const u16* __restrict__ B,
               int N, int K,
               const int* __restrict__ meta,
               float* __restrict__ outf, u16* __restrict__ outh,
               const float* __restrict__ bias,
               float* __restrict__ aux,
               const float* __restrict__ rowscale) {
  __shared__ u16 Ah[128 * 32];
  __shared__ u16 Bh[128 * 32];
  __shared__ float lsh[128];

  const int tid  = threadIdx.x;
  const int wave = tid >> 6, lane = tid & 63;
  const int wr = (wave >> 1) * 64, wc = (wave & 1) * 64;

  int rb, cb0, cb_end, cb_step, kiters;
  if (EPI == EPI_QPROJ) {
    rb = blockIdx.y; cb0 = blockIdx.x; cb_end = cb0 + 1; cb_step = 1; kiters = K >> 5;
  } else if (EPI == EPI_MW) {
    rb = blockIdx.y; cb0 = blockIdx.x; cb_end = meta[1] >> 7; cb_step = 16; kiters = K >> 5;
  } else if (EPI == EPI_P) {
    // grid (16,128): group all 16 col-blocks of a row-block on one XCD
    int id = blockIdx.x + (blockIdx.y << 4);
    int xcd = id & 7, s = id >> 3;
    rb = xcd * 16 + (s >> 4); cb0 = s & 15;
    cb_end = meta[1] >> 7; cb_step = 16; kiters = K >> 5;
  } else { // EPI_OUT
    // grid (4,128): group the 4 col-blocks of a row-block on one XCD
    int id = blockIdx.x + (blockIdx.y << 2);
    int xcd = id & 7, s = id >> 3;
    rb = xcd * 16 + (s >> 2); cb0 = s & 3;
    cb_end = cb0 + 1; cb_step = 1; kiters = meta[2];
  }
  const int row0 = rb << 7;

  // staging lane map: row = lane&15 within a 16-row slab, k-chunk = lane>>4
  const int srow   = lane & 15;
  const int schunk = lane >> 4;
  const size_t aOff0 = (size_t)(row0 + wave * 16 + srow)       * (size_t)K + schunk * 8;
  const size_t aOff1 = (size_t)(row0 + (wave + 4) * 16 + srow) * (size_t)K + schunk * 8;
  u16* ldsA0 = &Ah[(wave)     * 512];
  u16* ldsA1 = &Ah[(wave + 4) * 512];
  u16* ldsB0 = &Bh[(wave)     * 512];
  u16* ldsB1 = &Bh[(wave + 4) * 512];

  const int fr = lane & 15;         // fragment row (A: m, B: n)
  const int q4 = lane >> 4;         // fragment k-chunk

  for (int cb = cb0; cb < cb_end; cb += cb_step) {
    const int col0 = cb << 7;
    __syncthreads();                            // guard lsh/LDS reuse across cb iters
    if ((EPI == EPI_QPROJ || EPI == EPI_P) && tid < 128) lsh[tid] = 0.0f;

    const size_t bOff0 = (size_t)(col0 + wave * 16 + srow)       * (size_t)K + schunk * 8;
    const size_t bOff1 = (size_t)(col0 + (wave + 4) * 16 + srow) * (size_t)K + schunk * 8;

    f32x4 acc[4][4];
    const f32x4 z = {0.0f, 0.0f, 0.0f, 0.0f};
    #pragma unroll
    for (int i = 0; i < 4; ++i)
      #pragma unroll
      for (int j = 0; j < 4; ++j) acc[i][j] = z;

    for (int it = 0; it < kiters; ++it) {
      const int k0 = it << 5;
      __syncthreads();   // prior iteration's LDS reads drained
      __builtin_amdgcn_global_load_lds((gp_t)(A + aOff0 + k0), (lp_t)ldsA0, 16, 0, 0);
      __builtin_amdgcn_global_load_lds((gp_t)(A + aOff1 + k0), (lp_t)ldsA1, 16, 0, 0);
      __builtin_amdgcn_global_load_lds((gp_t)(B + bOff0 + k0), (lp_t)ldsB0, 16, 0, 0);
      __builtin_amdgcn_global_load_lds((gp_t)(B + bOff1 + k0), (lp_t)ldsB1, 16, 0, 0);
      __syncthreads();   // staging drained (vmcnt(0) before barrier)

      bf16x8 af[4], bfv[4];
      #pragma unroll
      for (int i = 0; i < 4; ++i)
        af[i] = *(const bf16x8*)&Ah[((wr >> 4) + i) * 512 + q4 * 128 + fr * 8];
      #pragma unroll
      for (int j = 0; j < 4; ++j)
        bfv[j] = *(const bf16x8*)&Bh[((wc >> 4) + j) * 512 + q4 * 128 + fr * 8];

      #pragma unroll
      for (int i = 0; i < 4; ++i)
        #pragma unroll
        for (int j = 0; j < 4; ++j)
          acc[i][j] = __builtin_amdgcn_mfma_f32_16x16x32_bf16(af[i], bfv[j], acc[i][j], 0, 0, 0);
    }

    // Epilogue. C/D layout per 16x16 tile: col = lane&15, row = (lane>>4)*4 + reg.
    if (EPI == EPI_QPROJ) {
      float bv[4];
      #pragma unroll
      for (int j = 0; j < 4; ++j) bv[j] = bias[col0 + wc + j * 16 + fr];
      #pragma unroll
      for (int i = 0; i < 4; ++i) {
        #pragma unroll
        for (int r = 0; r < 4; ++r) {
          int lrow = wr + i * 16 + (lane >> 4) * 4 + r;
          size_t grow = (size_t)(row0 + lrow);
          float s = 0.0f;
          #pragma unroll
          for (int j = 0; j < 4; ++j) {
            int gcol = col0 + wc + j * 16 + fr;
            float v = acc[i][j][r] + bv[j];
            outh[grow * (size_t)N + gcol] = f2b(v);
            s += v * v;
          }
          #pragma unroll
          for (int d = 1; d < 16; d <<= 1) s += __shfl_xor(s, d, 64);
          if (fr == 0) atomicAdd(&lsh[lrow], s);
        }
      }
      __syncthreads();
      if (tid < 128) aux[(size_t)(row0 + tid) * 4 + cb] = lsh[tid];
    } else if (EPI == EPI_MW) {
      #pragma unroll
      for (int i = 0; i < 4; ++i) {
        #pragma unroll
        for (int r = 0; r < 4; ++r) {
          int grow = row0 + wr + i * 16 + (lane >> 4) * 4 + r;
          #pragma unroll
          for (int j = 0; j < 4; ++j) {
            int gcol = col0 + wc + j * 16 + fr;
            outh[(size_t)grow * (size_t)N + gcol] = f2b(acc[i][j][r]);
          }
        }
      }
    } else if (EPI == EPI_P) {
      const int count = meta[0];
      #pragma unroll
      for (int i = 0; i < 4; ++i) {
        #pragma unroll
        for (int r = 0; r < 4; ++r) {
          int lrow = wr + i * 16 + (lane >> 4) * 4 + r;
          size_t grow = (size_t)(row0 + lrow);
          float rq10 = rowscale[grow] * 10.0f;
          float s = 0.0f;
          #pragma unroll
          for (int j = 0; j < 4; ++j) {
            int gcol = col0 + wc + j * 16 + fr;
            float p = (gcol < count) ? __expf(acc[i][j][r] * rq10) : 0.0f;
            outh[grow * (size_t)N + gcol] = f2b(p);
            s += p;
          }
          #pragma unroll
          for (int d = 1; d < 16; d <<= 1) s += __shfl_xor(s, d, 64);
          if (fr == 0) atomicAdd(&lsh[lrow], s);
        }
      }
      __syncthreads();
      if (tid < 128) aux[(size_t)(row0 + tid) * 32 + cb] = lsh[tid];
    } else {  // EPI_OUT
      float bv[4];
      #pragma unroll
      for (int j = 0; j < 4; ++j) bv[j] = bias[col0 + wc + j * 16 + fr];
      #pragma unroll
      for (int i = 0; i < 4; ++i) {
        #pragma unroll
        for (int r = 0; r < 4; ++r) {
          int grow = row0 + wr + i * 16 + (lane >> 4) * 4 + r;
          float sc = rowscale[grow];
          #pragma unroll
          for (int j = 0; j < 4; ++j) {
            int gcol = col0 + wc + j * 16 + fr;
            outf[(size_t)grow * (size_t)N + gcol] = acc[i][j][r] * sc + bv[j];
          }
        }
      }
    }
  }
}

extern "C" void kernel_launch(void* const* d_in, const int* in_sizes, int n_in,
                              void* d_out, int out_size, void* d_ws, size_t ws_size,
                              hipStream_t stream) {
  const float* hidden = (const float*)d_in[0];   // [16384, 512]
  const float* mkeys  = (const float*)d_in[1];   // [4096, 512]
  const float* mvals  = (const float*)d_in[2];   // [4096, 512]
  const float* Wk     = (const float*)d_in[3];   // [512, 512]
  const float* bk     = (const float*)d_in[4];   // [512]
  const float* Wo     = (const float*)d_in[5];   // [512, 512]
  const float* bo     = (const float*)d_in[6];   // [512]
  const int*   usage  = (const int*)d_in[7];     // [4096]
  (void)in_sizes; (void)n_in; (void)out_size; (void)ws_size;

  char* ws = (char*)d_ws;
  // hb region [0,16MB): bf16 hidden during q-proj; dead afterwards -> idx/meta overlay.
  u16*   hb    = (u16*)(ws + 0);            //  16,777,216  hidden bf16 (early)
  int*   idx   = (int*)(ws + 0);            //      16,384  compacted->orig map (late)
  int*   meta  = (int*)(ws + 16384);        //          16  {count, K_eff, K_eff/32, K_eff/128}
  u16*   wkb   = (u16*)(ws + 16777216);     //     524,288  Wk bf16
  u16*   wob   = (u16*)(ws + 17301504);     //     524,288  Wo bf16
  u16*   mkn   = (u16*)(ws + 17825792);     //   4,194,304  compacted normalized keys bf16
  u16*   mv_c  = (u16*)(ws + 22020096);     //   4,194,304  compacted mvals bf16
  u16*   qb    = (u16*)(ws + 26214400);     //  16,777,216  q bf16 (unnormalized, +bk)
  u16*   MWt   = (u16*)(ws + 42991616);     //   4,194,304  (mvals@Wo^T)^T bf16 [512,4096]
  u16*   P     = (u16*)(ws + 47185920);     // 134,217,728  exp-scores bf16 [16384,4096]
  float* qss   = (float*)(ws + 181403648);  //     262,144  q sumsq partials [16384,4]
  float* rsqQ  = (float*)(ws + 181665792);  //      65,536  rsqrt(|q|^2+eps) [16384]
  float* lpart = (float*)(ws + 181731328);  //   2,097,152  row-sum partials [16384,32]
  float* linv  = (float*)(ws + 183828480);  //      65,536  1/rowsum [16384]
  // total: 183,894,016 bytes

  // casts
  k_f2bf<<<8192, 256, 0, stream>>>(hidden, hb, 2097152);
  k_f2bf<<<256, 256, 0, stream>>>(Wk, wkb, 65536);
  k_f2bf<<<256, 256, 0, stream>>>(Wo, wob, 65536);

  // q = hidden @ Wk^T + bk -> bf16 qb + sumsq partials (norm folded out)
  k_gemm_bt<EPI_QPROJ><<<dim3(4, 128), 256, 0, stream>>>(hb, wkb, 512, 512,
      nullptr, nullptr, qb, bk, qss, nullptr);
  k_rsq<<<64, 256, 0, stream>>>(qss, rsqQ);

  // compaction of the memory bank (hb now dead)
  k_compact<<<1, 256, 0, stream>>>(usage, idx, meta);
  k_gather_norm<<<1024, 256, 0, stream>>>(mkeys, idx, meta, mkn);
  k_gather<<<1024, 256, 0, stream>>>(mvals, idx, meta, mv_c);

  // MWt[h, m] = sum_v Wo[h,v] * mvals_c[m,v]  (Wo folded into V)
  k_gemm_bt<EPI_MW><<<dim3(16, 4), 256, 0, stream>>>(wob, mv_c, M_DIM, 512,
      meta, nullptr, MWt, nullptr, nullptr, nullptr);

  // P = exp(10 * (qb @ mkn^T) * rsqQ[r]) over active slots; partial row sums
  k_gemm_bt<EPI_P><<<dim3(16, 128), 256, 0, stream>>>(qb, mkn, M_DIM, 512,
      meta, nullptr, P, nullptr, lpart, rsqQ);
  k_reduce_l<<<64, 256, 0, stream>>>(lpart, linv, meta);

  // out = (P @ MWt^T) * linv[r] + bo   (fp32, direct to d_out)
  k_gemm_bt<EPI_OUT><<<dim3(4, 128), 256, 0, stream>>>(P, MWt, 512, M_DIM,
      meta, (float*)d_out, nullptr, bo, nullptr, linv);
}